// Round 9
// baseline (202.266 us; speedup 1.0000x reference)
//
#include <hip/hip_runtime.h>
#include <hip/hip_bf16.h>

#define NN 8192
#define KIN 512
#define KOUT 256
#define ALPHA 0.2f
#define BK 64
#define ROWS 128        // rows per block
#define KQ (NN / 4)     // k-range per quarter
#define NT4 (KQ / BK)   // 32 k-tiles per quarter

typedef __bf16 bf16x8 __attribute__((ext_vector_type(8)));
typedef float f32x4 __attribute__((ext_vector_type(4)));
typedef unsigned short ushort8_t __attribute__((ext_vector_type(8)));
typedef unsigned short ushort4_t __attribute__((ext_vector_type(4)));

__device__ __forceinline__ float lrelu(float x) { return x > 0.f ? x : ALPHA * x; }

__device__ __forceinline__ unsigned short f2bf(float f) {
  union { float f; unsigned u; } v; v.f = f;
  unsigned r = v.u + 0x7fffu + ((v.u >> 16) & 1u);  // RNE to bf16
  return (unsigned short)(r >> 16);
}
__device__ __forceinline__ float bf2f(unsigned short b) {
  union { unsigned u; float f; } v; v.u = ((unsigned)b) << 16;
  return v.f;
}

// ---------------- k_pack: adj (int32) -> bitmask (1 bit/elem, 8 MB) -------
// chunk c covers elements [c*64, c*64+64); bit l of BM[c] = adj[c*64+l] > 0
__global__ __launch_bounds__(256) void k_pack(const int* __restrict__ adj,
                                              unsigned long long* __restrict__ BM) {
  const unsigned gw = blockIdx.x * 4 + (threadIdx.x >> 6);
  const unsigned lane = threadIdx.x & 63;
  const unsigned nw = gridDim.x * 4;
  const unsigned nchunk = (unsigned)((size_t)NN * NN / 64);
  for (unsigned c = gw; c < nchunk; c += nw) {
    int a = adj[(size_t)c * 64 + lane];
    unsigned long long m = __ballot(a > 0);
    if (lane == 0) BM[c] = m;
  }
}

// ---------------- k1: Wh = h @ W (fp32), fused src/dst, store Wh as bf16 ----
__global__ __launch_bounds__(512) void k_wh(const float* __restrict__ h,
                                            const float* __restrict__ W,
                                            const float* __restrict__ a1,
                                            const float* __restrict__ a2,
                                            unsigned short* __restrict__ WhB,
                                            float* __restrict__ src,
                                            float* __restrict__ dstv) {
  __shared__ float sA[16][36];    // [k][row]
  __shared__ float sB[16][260];   // [k][col]
  const int tid = threadIdx.x;
  const int wave = tid >> 6;
  const int lane = tid & 63;
  const int bm = blockIdx.x * 32;
  const int arow = tid >> 4;
  const int akk = tid & 15;
  const int bkr = tid >> 5;
  const int bc = (tid & 31) * 8;
  float acc[4][4] = {};
  for (int k0 = 0; k0 < KIN; k0 += 16) {
    float av = h[(size_t)(bm + arow) * KIN + k0 + akk];
    const float4* wp = (const float4*)(W + (size_t)(k0 + bkr) * KOUT + bc);
    float4 w0 = wp[0], w1 = wp[1];
    __syncthreads();
    sA[akk][arow] = av;
    *(float4*)&sB[bkr][bc] = w0;
    *(float4*)&sB[bkr][bc + 4] = w1;
    __syncthreads();
#pragma unroll
    for (int k = 0; k < 16; ++k) {
      float4 a4 = *(const float4*)&sA[k][wave * 4];
      float4 b4 = *(const float4*)&sB[k][lane * 4];
      float aa[4] = {a4.x, a4.y, a4.z, a4.w};
      float bb[4] = {b4.x, b4.y, b4.z, b4.w};
#pragma unroll
      for (int i = 0; i < 4; ++i)
#pragma unroll
        for (int jj = 0; jj < 4; ++jj)
          acc[i][jj] = fmaf(aa[i], bb[jj], acc[i][jj]);
    }
  }
  float4 a1v = *(const float4*)(a1 + lane * 4);
  float4 a2v = *(const float4*)(a2 + lane * 4);
  float sp[4], dp[4];
#pragma unroll
  for (int i = 0; i < 4; ++i) {
    sp[i] = acc[i][0] * a1v.x + acc[i][1] * a1v.y + acc[i][2] * a1v.z + acc[i][3] * a1v.w;
    dp[i] = acc[i][0] * a2v.x + acc[i][1] * a2v.y + acc[i][2] * a2v.z + acc[i][3] * a2v.w;
  }
#pragma unroll
  for (int off = 32; off >= 1; off >>= 1) {
#pragma unroll
    for (int i = 0; i < 4; ++i) {
      sp[i] += __shfl_xor(sp[i], off);
      dp[i] += __shfl_xor(dp[i], off);
    }
  }
  if (lane == 0) {
#pragma unroll
    for (int i = 0; i < 4; ++i) {
      src[bm + wave * 4 + i] = sp[i];
      dstv[bm + wave * 4 + i] = dp[i];
    }
  }
#pragma unroll
  for (int i = 0; i < 4; ++i) {
    ushort4_t pk;
#pragma unroll
    for (int jj = 0; jj < 4; ++jj) pk[jj] = f2bf(acc[i][jj]);
    *(ushort4_t*)(WhB + (size_t)(bm + wave * 4 + i) * KOUT + lane * 4) = pk;
  }
}

// ---------------- k_tr: WhT[c][r] = WhB[r][c] ----------------
__global__ __launch_bounds__(256) void k_tr(const unsigned short* __restrict__ WhB,
                                            unsigned short* __restrict__ WhT) {
  __shared__ unsigned int sX[64][65];
  const int t = threadIdx.x;
  const int r0 = (blockIdx.x & 127) * 64;
  const int c0 = (blockIdx.x >> 7) * 64;
  const int rr = t >> 2;
  const int cq = (t & 3) * 16;
  const ushort8_t* p = (const ushort8_t*)(WhB + (size_t)(r0 + rr) * KOUT + c0 + cq);
  ushort8_t v0 = p[0], v1 = p[1];
#pragma unroll
  for (int i = 0; i < 8; ++i) {
    sX[rr][cq + i] = v0[i];
    sX[rr][cq + 8 + i] = v1[i];
  }
  __syncthreads();
  const int cc = t >> 2;
  const int r8 = (t & 3) * 16;
  ushort8_t o0, o1;
#pragma unroll
  for (int i = 0; i < 8; ++i) {
    o0[i] = (unsigned short)sX[r8 + i][cc];
    o1[i] = (unsigned short)sX[r8 + 8 + i][cc];
  }
  ushort8_t* q = (ushort8_t*)(WhT + (size_t)(c0 + cc) * NN + r0 + r8);
  q[0] = o0;
  q[1] = o1;
}

// ---------------- k_dmax ----------------
__global__ __launch_bounds__(256) void k_dmax(const float* __restrict__ dstv,
                                              float* __restrict__ Dp) {
  __shared__ float red[256];
  const int t = threadIdx.x;
  float m = -3e38f;
  for (int i = t; i < NN; i += 256) m = fmaxf(m, dstv[i]);
  red[t] = m;
  __syncthreads();
  for (int s = 128; s >= 1; s >>= 1) {
    if (t < s) red[t] = fmaxf(red[t], red[t + s]);
    __syncthreads();
  }
  if (t == 0) *Dp = red[0];
}

// ---- k_attn: 128-row blocks, K-split x4, wave-specialized, bitmask adj ---
struct Bset { ushort8_t b[2][2]; };  // [col-half][kk]

#define MF(a, b, c) __builtin_amdgcn_mfma_f32_16x16x32_bf16(a, b, c, 0, 0, 0)

#define BAR()                                              \
  {                                                        \
    asm volatile("s_waitcnt lgkmcnt(0)" ::: "memory");     \
    __builtin_amdgcn_s_barrier();                          \
    asm volatile("" ::: "memory");                         \
  }

// virtual phase t -> LOCAL k-tile in this quarter (per-block rotation)
#define TI(t) (((t) + ph0) & (NT4 - 1))

#define LOADB(BS, ktl)                                                 \
  {                                                                    \
    const size_t kb = (size_t)(ktl) * BK + fq * 8;                     \
    BS.b[0][0] = *(const ushort8_t*)(bpw0 + kb);                       \
    BS.b[0][1] = *(const ushort8_t*)(bpw0 + kb + 32);                  \
    BS.b[1][0] = *(const ushort8_t*)(bpw1 + kb);                       \
    BS.b[1][1] = *(const ushort8_t*)(bpw1 + kb + 32);                  \
  }

// producer: 4 weights from 4 mask bits at local k-offset koff
#define WGEN4(BITS, ktl, koff, buf)                                    \
  {                                                                    \
    float4 dv = *(const float4*)&sD[(ktl) * BK + (koff)];              \
    float w0 = ((BITS) & 1u) ? __expf(lrelu(s_r + dv.x) - c_r) : 0.f;  \
    float w1 = ((BITS) & 2u) ? __expf(lrelu(s_r + dv.y) - c_r) : 0.f;  \
    float w2 = ((BITS) & 4u) ? __expf(lrelu(s_r + dv.z) - c_r) : 0.f;  \
    float w3 = ((BITS) & 8u) ? __expf(lrelu(s_r + dv.w) - c_r) : 0.f;  \
    unsigned short u0 = f2bf(w0), u1 = f2bf(w1);                       \
    unsigned short u2 = f2bf(w2), u3 = f2bf(w3);                       \
    lsum += bf2f(u0) + bf2f(u1) + bf2f(u2) + bf2f(u3);                 \
    uint2 pk;                                                          \
    pk.x = (unsigned)u0 | ((unsigned)u1 << 16);                        \
    pk.y = (unsigned)u2 | ((unsigned)u3 << 16);                        \
    *(uint2*)(sAb + (buf) * 16384 +                                    \
              ((pr * 128 + (koff) * 2) ^ ((pr & 7) << 4))) = pk;       \
  }

// producer phase body: 16 weights from one ushort of mask bits
#define WGEN16(BITS, ktl, buf)                                         \
  {                                                                    \
    unsigned bb_ = (unsigned)(BITS);                                   \
    WGEN4(bb_, ktl, pk16 + 0, buf);                                    \
    WGEN4(bb_ >> 4, ktl, pk16 + 4, buf);                               \
    WGEN4(bb_ >> 8, ktl, pk16 + 8, buf);                               \
    WGEN4(bb_ >> 12, ktl, pk16 + 12, buf);                             \
  }

#define LDA(cur, mr, kk)                                                        \
  __builtin_bit_cast(bf16x8,                                                    \
    *(const ushort8_t*)(sAb + (cur) * 16384 +                                   \
      ((((mr) * 16 + fr) * 128 + (kk) * 64 + fq * 16) ^ ((fr & 7) << 4))))

#define MSTEP(cur, BS)                                                 \
  {                                                                    \
    _Pragma("unroll")                                                  \
    for (int mr = 0; mr < 8; ++mr) {                                   \
      bf16x8 a0 = LDA(cur, mr, 0), a1 = LDA(cur, mr, 1);               \
      acc[mr][0] = MF(a0, BS.b[0][0], acc[mr][0]);                     \
      acc[mr][0] = MF(a1, BS.b[0][1], acc[mr][0]);                     \
      acc[mr][1] = MF(a0, BS.b[1][0], acc[mr][1]);                     \
      acc[mr][1] = MF(a1, BS.b[1][1], acc[mr][1]);                     \
    }                                                                  \
  }

__global__ __launch_bounds__(1024) void k_attn(const unsigned short* __restrict__ BM16,
                                               const unsigned short* __restrict__ WhT,
                                               const float* __restrict__ src,
                                               const float* __restrict__ dstv,
                                               const float* __restrict__ Dp,
                                               float* __restrict__ Pbuf,
                                               float* __restrict__ Lsum) {
  __shared__ unsigned short sA[2][ROWS][BK];  // 32 KB dbuf, XOR-swizzled rows
  __shared__ float sD[KQ];                    // 8 KB: this quarter's dstv
  char* sAb = (char*)&sA[0][0][0];
  const int tid = threadIdx.x;
  const int lane = tid & 63;
  const int wave = tid >> 6;      // 0..7 consumers, 8..15 producers
  const int qtr = blockIdx.x & 3;
  const int rg = blockIdx.x >> 2;
  const int r0 = rg * ROWS;
  const int ph0 = rg & (NT4 - 1);
  const int kbase = qtr * KQ;
  const float D = *Dp;

  // stage this quarter's dstv slice -> LDS
  *(float2*)&sD[tid * 2] = *(const float2*)(dstv + kbase + tid * 2);
  __syncthreads();

  // ---------- producer state (waves 8..15): 4 threads per row ----------
  const int ptid = tid - 512;               // 0..511
  const int pr = ptid >> 2;                 // 0..127
  const int pk16 = (ptid & 3) * 16;         // k-offset within tile
  const float s_r = src[r0 + pr];
  const float c_r = lrelu(s_r + D);
  // BM16[(row*128 + chunk)*4 + q]: bits [q*16, q*16+16) of 64-elem chunk
  const unsigned short* bmp =
      BM16 + ((size_t)(r0 + pr) * 128 + kbase / 64) * 4 + (ptid & 3);
  float lsum = 0.f;

  // ---------- consumer state (waves 0..7): wave tile 128x32 ----------
  const int fr = lane & 15;
  const int fq = lane >> 4;
  const unsigned short* bpw0 = WhT + (size_t)(wave * 32 + fr) * NN + kbase;
  const unsigned short* bpw1 = WhT + (size_t)(wave * 32 + 16 + fr) * NN + kbase;
  f32x4 acc[8][2];
#pragma unroll
  for (int mr = 0; mr < 8; ++mr) {
    acc[mr][0] = (f32x4){0.f, 0.f, 0.f, 0.f};
    acc[mr][1] = (f32x4){0.f, 0.f, 0.f, 0.f};
  }
  Bset B0, B1;
  unsigned short bA, bB;  // bitmask slack slots (even/odd tiles)

  // ---------- prologue ----------
  if (wave >= 8) {
    unsigned short b0 = bmp[(size_t)TI(0) * 4];
    WGEN16(b0, TI(0), 0);
    bB = bmp[(size_t)TI(1) * 4];
    bA = bmp[(size_t)TI(2) * 4];
  } else {
    LOADB(B0, TI(0));
    LOADB(B1, TI(1));
  }
  BAR();

  // ---------- main loop: NT4 phases, unrolled by 2 ----------
  if (wave < 8) {
#pragma unroll 1
    for (int p = 0; p < NT4; p += 2) {
      { MSTEP(0, B0); LOADB(B0, TI(p + 2)); BAR(); }
      { MSTEP(1, B1); LOADB(B1, TI(p + 3)); BAR(); }
    }
    // store raw partial accumulators
#pragma unroll
    for (int mr = 0; mr < 8; ++mr) {
#pragma unroll
      for (int r = 0; r < 4; ++r) {
        const int row = mr * 16 + fq * 4 + r;
#pragma unroll
        for (int nc = 0; nc < 2; ++nc) {
          const int col = wave * 32 + nc * 16 + fr;
          Pbuf[(size_t)(qtr * NN + r0 + row) * KOUT + col] = acc[mr][nc][r];
        }
      }
    }
  } else {
#pragma unroll 1
    for (int p = 0; p < NT4; p += 2) {
      // phase p: WGEN tile p+1 (slotB), reload slotB <- tile p+3
      {
        WGEN16(bB, TI(p + 1), 1);
        bB = bmp[(size_t)TI(p + 3) * 4];
        BAR();
      }
      // phase p+1: WGEN tile p+2 (slotA), reload slotA <- tile p+4
      {
        if (p + 2 < NT4) { WGEN16(bA, TI(p + 2), 0); }
        bA = bmp[(size_t)TI(p + 4) * 4];
        BAR();
      }
    }
    // row-sum reduce across the 4 threads sharing a row
    lsum += __shfl_xor(lsum, 1, 4);
    lsum += __shfl_xor(lsum, 2, 4);
    if ((ptid & 3) == 0) Lsum[qtr * NN + r0 + pr] = lsum;
  }
}

// ---------------- k_comb: out = elu(sum(P)/sum(L)) -----------------------
__global__ __launch_bounds__(256) void k_comb(const float* __restrict__ Pbuf,
                                              const float* __restrict__ Lsum,
                                              float* __restrict__ out) {
  const int t = threadIdx.x;
  const int row = blockIdx.x * 4 + (t >> 6);
  const int col = (t & 63) * 4;
  const float l = Lsum[row] + Lsum[NN + row] + Lsum[2 * NN + row] + Lsum[3 * NN + row];
  float4 p0 = *(const float4*)(Pbuf + (size_t)row * KOUT + col);
  float4 p1 = *(const float4*)(Pbuf + (size_t)(NN + row) * KOUT + col);
  float4 p2 = *(const float4*)(Pbuf + (size_t)(2 * NN + row) * KOUT + col);
  float4 p3 = *(const float4*)(Pbuf + (size_t)(3 * NN + row) * KOUT + col);
  float4 v;
  v.x = (p0.x + p1.x + p2.x + p3.x) / l;
  v.y = (p0.y + p1.y + p2.y + p3.y) / l;
  v.z = (p0.z + p1.z + p2.z + p3.z) / l;
  v.w = (p0.w + p1.w + p2.w + p3.w) / l;
  v.x = v.x > 0.f ? v.x : __expf(v.x) - 1.f;
  v.y = v.y > 0.f ? v.y : __expf(v.y) - 1.f;
  v.z = v.z > 0.f ? v.z : __expf(v.z) - 1.f;
  v.w = v.w > 0.f ? v.w : __expf(v.w) - 1.f;
  *(float4*)(out + (size_t)row * KOUT + col) = v;
}

extern "C" void kernel_launch(void* const* d_in, const int* in_sizes, int n_in,
                              void* d_out, int out_size, void* d_ws, size_t ws_size,
                              hipStream_t stream) {
  const float* h = (const float*)d_in[0];
  const int* adj = (const int*)d_in[1];
  const float* W = (const float*)d_in[2];
  const float* a1 = (const float*)d_in[3];
  const float* a2 = (const float*)d_in[4];
  float* out = (float*)d_out;

  unsigned short* WhB = (unsigned short*)d_ws;            // 4 MB
  unsigned short* WhT = WhB + (size_t)NN * KOUT;          // 4 MB
  float* src = (float*)(WhT + (size_t)NN * KOUT);         // 32 KB
  float* dstv = src + NN;                                 // 32 KB
  float* Dp = dstv + NN;                                  // pad
  float* Pbuf = Dp + 16;                                  // 32 MB partials
  float* Lsum = Pbuf + (size_t)4 * NN * KOUT;             // 128 KB
  unsigned long long* BM = (unsigned long long*)(Lsum + 4 * NN);  // 8 MB bitmask

  hipLaunchKernelGGL(k_pack, dim3(2048), dim3(256), 0, stream, adj, BM);
  hipLaunchKernelGGL(k_wh, dim3(NN / 32), dim3(512), 0, stream, h, W, a1, a2, WhB, src, dstv);
  hipLaunchKernelGGL(k_tr, dim3(512), dim3(256), 0, stream, WhB, WhT);
  hipLaunchKernelGGL(k_dmax, dim3(1), dim3(256), 0, stream, dstv, Dp);
  hipLaunchKernelGGL(k_attn, dim3(256), dim3(1024), 0, stream,
                     (const unsigned short*)BM, WhT, src, dstv, Dp, Pbuf, Lsum);
  hipLaunchKernelGGL(k_comb, dim3(NN / 4), dim3(256), 0, stream, Pbuf, Lsum, out);
}

// Round 10
// 149.860 us; speedup vs baseline: 1.3497x; 1.3497x over previous
//
#include <hip/hip_runtime.h>
#include <hip/hip_bf16.h>

#define NN 8192
#define KIN 512
#define KOUT 256
#define ALPHA 0.2f
#define BK 64
#define ROWS 128        // rows per block
#define KQ (NN / 4)     // k-range per quarter
#define NT4 (KQ / BK)   // 32 k-tiles per quarter

typedef __bf16 bf16x8 __attribute__((ext_vector_type(8)));
typedef float f32x4 __attribute__((ext_vector_type(4)));
typedef unsigned short ushort8_t __attribute__((ext_vector_type(8)));
typedef unsigned short ushort4_t __attribute__((ext_vector_type(4)));
typedef int int4v __attribute__((ext_vector_type(4)));

__device__ __forceinline__ float lrelu(float x) { return x > 0.f ? x : ALPHA * x; }

__device__ __forceinline__ unsigned short f2bf(float f) {
  union { float f; unsigned u; } v; v.f = f;
  unsigned r = v.u + 0x7fffu + ((v.u >> 16) & 1u);  // RNE to bf16
  return (unsigned short)(r >> 16);
}
__device__ __forceinline__ float bf2f(unsigned short b) {
  union { unsigned u; float f; } v; v.u = ((unsigned)b) << 16;
  return v.f;
}

// ---------------- k1: Wh = h @ W (fp32), fused src/dst, store Wh as bf16 ----
__global__ __launch_bounds__(512) void k_wh(const float* __restrict__ h,
                                            const float* __restrict__ W,
                                            const float* __restrict__ a1,
                                            const float* __restrict__ a2,
                                            unsigned short* __restrict__ WhB,
                                            float* __restrict__ src,
                                            float* __restrict__ dstv) {
  __shared__ float sA[16][36];    // [k][row]
  __shared__ float sB[16][260];   // [k][col]
  const int tid = threadIdx.x;
  const int wave = tid >> 6;
  const int lane = tid & 63;
  const int bm = blockIdx.x * 32;
  const int arow = tid >> 4;
  const int akk = tid & 15;
  const int bkr = tid >> 5;
  const int bc = (tid & 31) * 8;
  float acc[4][4] = {};
  for (int k0 = 0; k0 < KIN; k0 += 16) {
    float av = h[(size_t)(bm + arow) * KIN + k0 + akk];
    const float4* wp = (const float4*)(W + (size_t)(k0 + bkr) * KOUT + bc);
    float4 w0 = wp[0], w1 = wp[1];
    __syncthreads();
    sA[akk][arow] = av;
    *(float4*)&sB[bkr][bc] = w0;
    *(float4*)&sB[bkr][bc + 4] = w1;
    __syncthreads();
#pragma unroll
    for (int k = 0; k < 16; ++k) {
      float4 a4 = *(const float4*)&sA[k][wave * 4];
      float4 b4 = *(const float4*)&sB[k][lane * 4];
      float aa[4] = {a4.x, a4.y, a4.z, a4.w};
      float bb[4] = {b4.x, b4.y, b4.z, b4.w};
#pragma unroll
      for (int i = 0; i < 4; ++i)
#pragma unroll
        for (int jj = 0; jj < 4; ++jj)
          acc[i][jj] = fmaf(aa[i], bb[jj], acc[i][jj]);
    }
  }
  float4 a1v = *(const float4*)(a1 + lane * 4);
  float4 a2v = *(const float4*)(a2 + lane * 4);
  float sp[4], dp[4];
#pragma unroll
  for (int i = 0; i < 4; ++i) {
    sp[i] = acc[i][0] * a1v.x + acc[i][1] * a1v.y + acc[i][2] * a1v.z + acc[i][3] * a1v.w;
    dp[i] = acc[i][0] * a2v.x + acc[i][1] * a2v.y + acc[i][2] * a2v.z + acc[i][3] * a2v.w;
  }
#pragma unroll
  for (int off = 32; off >= 1; off >>= 1) {
#pragma unroll
    for (int i = 0; i < 4; ++i) {
      sp[i] += __shfl_xor(sp[i], off);
      dp[i] += __shfl_xor(dp[i], off);
    }
  }
  if (lane == 0) {
#pragma unroll
    for (int i = 0; i < 4; ++i) {
      src[bm + wave * 4 + i] = sp[i];
      dstv[bm + wave * 4 + i] = dp[i];
    }
  }
#pragma unroll
  for (int i = 0; i < 4; ++i) {
    ushort4_t pk;
#pragma unroll
    for (int jj = 0; jj < 4; ++jj) pk[jj] = f2bf(acc[i][jj]);
    *(ushort4_t*)(WhB + (size_t)(bm + wave * 4 + i) * KOUT + lane * 4) = pk;
  }
}

// ---- k_trF: WhB[row][col] -> WhF in exact MFMA B-fragment order ----------
// chunk index: (((kt*8 + w)*2 + nc)*2 + kh)*64 + lane  (x8 ushorts)
// chunk content: Wh[kt*64 + kh*32 + (lane>>4)*8 + e][w*32 + nc*16 + (lane&15)]
__global__ __launch_bounds__(256) void k_trF(const unsigned short* __restrict__ WhB,
                                             unsigned short* __restrict__ WhF) {
  __shared__ unsigned int sX[64][65];
  const int t = threadIdx.x;
  const int r0 = (blockIdx.x & 127) * 64;
  const int c0 = (blockIdx.x >> 7) * 64;
  const int rr = t >> 2;
  const int cq = (t & 3) * 16;
  const ushort8_t* p = (const ushort8_t*)(WhB + (size_t)(r0 + rr) * KOUT + c0 + cq);
  ushort8_t v0 = p[0], v1 = p[1];
#pragma unroll
  for (int i = 0; i < 8; ++i) {
    sX[rr][cq + i] = v0[i];
    sX[rr][cq + 8 + i] = v1[i];
  }
  __syncthreads();
  const int wv = t >> 6;
  const int lane = t & 63;
  const int q = lane >> 4;
  const int fr = lane & 15;
  const int kt = r0 >> 6;
  const int wbase = c0 >> 5;
#pragma unroll
  for (int i = 0; i < 2; ++i) {
    const int g = wv * 2 + i;            // 0..7
    const int wloc = g >> 2;
    const int nc = (g >> 1) & 1;
    const int kh = g & 1;
    const int j0 = kh * 32 + q * 8;
    const int lc = wloc * 32 + nc * 16 + fr;
    ushort8_t o;
#pragma unroll
    for (int e = 0; e < 8; ++e) o[e] = (unsigned short)sX[j0 + e][lc];
    const int w = wbase + wloc;
    const size_t idx = ((((size_t)kt * 8 + w) * 2 + nc) * 2 + kh) * 64 + lane;
    *(ushort8_t*)(WhF + idx * 8) = o;
  }
}

// ---------------- k_dmax ----------------
__global__ __launch_bounds__(256) void k_dmax(const float* __restrict__ dstv,
                                              float* __restrict__ Dp) {
  __shared__ float red[256];
  const int t = threadIdx.x;
  float m = -3e38f;
  for (int i = t; i < NN; i += 256) m = fmaxf(m, dstv[i]);
  red[t] = m;
  __syncthreads();
  for (int s = 128; s >= 1; s >>= 1) {
    if (t < s) red[t] = fmaxf(red[t], red[t + s]);
    __syncthreads();
  }
  if (t == 0) *Dp = red[0];
}

// ---- k_attn: 128-row blocks, K-split x4, wave-spec, fragment-ordered B ---
struct Bset { ushort8_t b[2][2]; };  // [nc][kh]

#define MF(a, b, c) __builtin_amdgcn_mfma_f32_16x16x32_bf16(a, b, c, 0, 0, 0)

#define BAR()                                              \
  {                                                        \
    asm volatile("s_waitcnt lgkmcnt(0)" ::: "memory");     \
    __builtin_amdgcn_s_barrier();                          \
    asm volatile("" ::: "memory");                         \
  }

// virtual phase t -> LOCAL k-tile in this quarter (per-block rotation)
#define TI(t) (((t) + ph0) & (NT4 - 1))

// fully-coalesced fragment loads: 4 x 1KB contiguous per wave
#define LOADB(BS, ktl)                                                 \
  {                                                                    \
    const unsigned short* p_ = bfw + (size_t)(ktl) * 16384;            \
    BS.b[0][0] = *(const ushort8_t*)(p_);                              \
    BS.b[0][1] = *(const ushort8_t*)(p_ + 512);                        \
    BS.b[1][0] = *(const ushort8_t*)(p_ + 1024);                       \
    BS.b[1][1] = *(const ushort8_t*)(p_ + 1536);                       \
  }

// producer: 4 weights at local k-offset koff (within tile), write to LDS buf
#define WGEN4(AJ, ktl, koff, buf)                                      \
  {                                                                    \
    float4 dv = *(const float4*)&sD[(ktl) * BK + (koff)];              \
    float w0 = (AJ.x > 0) ? __expf(lrelu(s_r + dv.x) - c_r) : 0.f;     \
    float w1 = (AJ.y > 0) ? __expf(lrelu(s_r + dv.y) - c_r) : 0.f;     \
    float w2 = (AJ.z > 0) ? __expf(lrelu(s_r + dv.z) - c_r) : 0.f;     \
    float w3 = (AJ.w > 0) ? __expf(lrelu(s_r + dv.w) - c_r) : 0.f;     \
    unsigned short u0 = f2bf(w0), u1 = f2bf(w1);                       \
    unsigned short u2 = f2bf(w2), u3 = f2bf(w3);                       \
    lsum += bf2f(u0) + bf2f(u1) + bf2f(u2) + bf2f(u3);                 \
    uint2 pk;                                                          \
    pk.x = (unsigned)u0 | ((unsigned)u1 << 16);                        \
    pk.y = (unsigned)u2 | ((unsigned)u3 << 16);                        \
    *(uint2*)(sAb + (buf) * 16384 +                                    \
              ((pr * 128 + (koff) * 2) ^ ((pr & 7) << 4))) = pk;       \
  }

// producer phase body: gen 16 weights (4 quads) for tile ktl into buf
#define WGEN16(A0, A1, A2, A3, ktl, buf)                               \
  {                                                                    \
    WGEN4(A0, ktl, pk16 + 0, buf);                                     \
    WGEN4(A1, ktl, pk16 + 4, buf);                                     \
    WGEN4(A2, ktl, pk16 + 8, buf);                                     \
    WGEN4(A3, ktl, pk16 + 12, buf);                                    \
  }

#define LOADADJ16(A0, A1, A2, A3, ktl)                                 \
  {                                                                    \
    const int4v* ap = (const int4v*)(adjp + (size_t)(ktl) * BK);       \
    A0 = __builtin_nontemporal_load(ap);                               \
    A1 = __builtin_nontemporal_load(ap + 1);                           \
    A2 = __builtin_nontemporal_load(ap + 2);                           \
    A3 = __builtin_nontemporal_load(ap + 3);                           \
  }

#define LDA(cur, mr, kk)                                                        \
  __builtin_bit_cast(bf16x8,                                                    \
    *(const ushort8_t*)(sAb + (cur) * 16384 +                                   \
      ((((mr) * 16 + fr) * 128 + (kk) * 64 + fq * 16) ^ ((fr & 7) << 4))))

#define MSTEP(cur, BS)                                                 \
  {                                                                    \
    _Pragma("unroll")                                                  \
    for (int mr = 0; mr < 8; ++mr) {                                   \
      bf16x8 a0 = LDA(cur, mr, 0), a1 = LDA(cur, mr, 1);               \
      acc[mr][0] = MF(a0, BS.b[0][0], acc[mr][0]);                     \
      acc[mr][0] = MF(a1, BS.b[0][1], acc[mr][0]);                     \
      acc[mr][1] = MF(a0, BS.b[1][0], acc[mr][1]);                     \
      acc[mr][1] = MF(a1, BS.b[1][1], acc[mr][1]);                     \
    }                                                                  \
  }

__global__ __launch_bounds__(1024) void k_attn(const int* __restrict__ adj,
                                               const unsigned short* __restrict__ WhF,
                                               const float* __restrict__ src,
                                               const float* __restrict__ dstv,
                                               const float* __restrict__ Dp,
                                               float* __restrict__ Pbuf,
                                               float* __restrict__ Lsum) {
  __shared__ unsigned short sA[2][ROWS][BK];  // 32 KB dbuf, XOR-swizzled rows
  __shared__ float sD[KQ];                    // 8 KB: this quarter's dstv
  char* sAb = (char*)&sA[0][0][0];
  const int tid = threadIdx.x;
  const int lane = tid & 63;
  const int wave = tid >> 6;      // 0..7 consumers, 8..15 producers
  const int qtr = blockIdx.x & 3;
  const int rg = blockIdx.x >> 2;
  const int r0 = rg * ROWS;
  const int ph0 = rg & (NT4 - 1);
  const int kbase = qtr * KQ;
  const float D = *Dp;

  // stage this quarter's dstv slice -> LDS
  *(float2*)&sD[tid * 2] = *(const float2*)(dstv + kbase + tid * 2);
  __syncthreads();

  // ---------- producer state (waves 8..15): 4 threads per row ----------
  const int ptid = tid - 512;               // 0..511
  const int pr = ptid >> 2;                 // 0..127
  const int pk16 = (ptid & 3) * 16;         // k-offset within tile
  const float s_r = src[r0 + pr];
  const float c_r = lrelu(s_r + D);
  const int* adjp = adj + (size_t)(r0 + pr) * NN + kbase + pk16;
  float lsum = 0.f;

  // ---------- consumer state (waves 0..7): wave tile 128x32 ----------
  const int fr = lane & 15;
  const int fq = lane >> 4;
  // fragment base for (k-tile qtr*NT4, this wave, this lane)
  const unsigned short* bfw =
      WhF + ((size_t)(qtr * NT4) * 8 + wave) * 2048 + lane * 8;
  f32x4 acc[8][2];
#pragma unroll
  for (int mr = 0; mr < 8; ++mr) {
    acc[mr][0] = (f32x4){0.f, 0.f, 0.f, 0.f};
    acc[mr][1] = (f32x4){0.f, 0.f, 0.f, 0.f};
  }
  Bset B0, B1;
  int4v aA0, aA1, aA2, aA3;   // adj slack slot A (even tiles)
  int4v aB0, aB1, aB2, aB3;   // adj slack slot B (odd tiles)

  // ---------- prologue ----------
  if (wave >= 8) {
    int4v d0, d1, d2, d3;
    {
      const int4v* ap = (const int4v*)(adjp + (size_t)TI(0) * BK);
      d0 = ap[0]; d1 = ap[1]; d2 = ap[2]; d3 = ap[3];
    }
    WGEN16(d0, d1, d2, d3, TI(0), 0);
    LOADADJ16(aB0, aB1, aB2, aB3, TI(1));
    LOADADJ16(aA0, aA1, aA2, aA3, TI(2));
  } else {
    LOADB(B0, TI(0));
    LOADB(B1, TI(1));
  }
  BAR();

  // ---------- main loop: NT4 phases, unrolled by 2 ----------
  if (wave < 8) {
#pragma unroll 1
    for (int p = 0; p < NT4; p += 2) {
      { MSTEP(0, B0); LOADB(B0, TI(p + 2)); BAR(); }
      { MSTEP(1, B1); LOADB(B1, TI(p + 3)); BAR(); }
    }
    // store raw partial accumulators
#pragma unroll
    for (int mr = 0; mr < 8; ++mr) {
#pragma unroll
      for (int r = 0; r < 4; ++r) {
        const int row = mr * 16 + fq * 4 + r;
#pragma unroll
        for (int nc = 0; nc < 2; ++nc) {
          const int col = wave * 32 + nc * 16 + fr;
          Pbuf[(size_t)(qtr * NN + r0 + row) * KOUT + col] = acc[mr][nc][r];
        }
      }
    }
  } else {
#pragma unroll 1
    for (int p = 0; p < NT4; p += 2) {
      {
        WGEN16(aB0, aB1, aB2, aB3, TI(p + 1), 1);
        LOADADJ16(aB0, aB1, aB2, aB3, TI(p + 3));
        BAR();
      }
      {
        if (p + 2 < NT4) { WGEN16(aA0, aA1, aA2, aA3, TI(p + 2), 0); }
        LOADADJ16(aA0, aA1, aA2, aA3, TI(p + 4));
        BAR();
      }
    }
    // row-sum reduce across the 4 threads sharing a row
    lsum += __shfl_xor(lsum, 1, 4);
    lsum += __shfl_xor(lsum, 2, 4);
    if ((ptid & 3) == 0) Lsum[qtr * NN + r0 + pr] = lsum;
  }
}

// ---------------- k_comb: out = elu(sum(P)/sum(L)) -----------------------
__global__ __launch_bounds__(256) void k_comb(const float* __restrict__ Pbuf,
                                              const float* __restrict__ Lsum,
                                              float* __restrict__ out) {
  const int t = threadIdx.x;
  const int row = blockIdx.x * 4 + (t >> 6);
  const int col = (t & 63) * 4;
  const float l = Lsum[row] + Lsum[NN + row] + Lsum[2 * NN + row] + Lsum[3 * NN + row];
  float4 p0 = *(const float4*)(Pbuf + (size_t)row * KOUT + col);
  float4 p1 = *(const float4*)(Pbuf + (size_t)(NN + row) * KOUT + col);
  float4 p2 = *(const float4*)(Pbuf + (size_t)(2 * NN + row) * KOUT + col);
  float4 p3 = *(const float4*)(Pbuf + (size_t)(3 * NN + row) * KOUT + col);
  float4 v;
  v.x = (p0.x + p1.x + p2.x + p3.x) / l;
  v.y = (p0.y + p1.y + p2.y + p3.y) / l;
  v.z = (p0.z + p1.z + p2.z + p3.z) / l;
  v.w = (p0.w + p1.w + p2.w + p3.w) / l;
  v.x = v.x > 0.f ? v.x : __expf(v.x) - 1.f;
  v.y = v.y > 0.f ? v.y : __expf(v.y) - 1.f;
  v.z = v.z > 0.f ? v.z : __expf(v.z) - 1.f;
  v.w = v.w > 0.f ? v.w : __expf(v.w) - 1.f;
  *(float4*)(out + (size_t)row * KOUT + col) = v;
}

extern "C" void kernel_launch(void* const* d_in, const int* in_sizes, int n_in,
                              void* d_out, int out_size, void* d_ws, size_t ws_size,
                              hipStream_t stream) {
  const float* h = (const float*)d_in[0];
  const int* adj = (const int*)d_in[1];
  const float* W = (const float*)d_in[2];
  const float* a1 = (const float*)d_in[3];
  const float* a2 = (const float*)d_in[4];
  float* out = (float*)d_out;

  unsigned short* WhB = (unsigned short*)d_ws;            // 4 MB
  unsigned short* WhF = WhB + (size_t)NN * KOUT;          // 4 MB (fragment order)
  float* src = (float*)(WhF + (size_t)NN * KOUT);         // 32 KB
  float* dstv = src + NN;                                 // 32 KB
  float* Dp = dstv + NN;                                  // pad
  float* Pbuf = Dp + 16;                                  // 32 MB partials
  float* Lsum = Pbuf + (size_t)4 * NN * KOUT;             // 128 KB

  hipLaunchKernelGGL(k_wh, dim3(NN / 32), dim3(512), 0, stream, h, W, a1, a2, WhB, src, dstv);
  hipLaunchKernelGGL(k_trF, dim3(512), dim3(256), 0, stream, WhB, WhF);
  hipLaunchKernelGGL(k_dmax, dim3(1), dim3(256), 0, stream, dstv, Dp);
  hipLaunchKernelGGL(k_attn, dim3(256), dim3(1024), 0, stream, adj, WhF, src, dstv, Dp, Pbuf, Lsum);
  hipLaunchKernelGGL(k_comb, dim3(NN / 4), dim3(256), 0, stream, Pbuf, Lsum, out);
}